// Round 13
// baseline (4134.995 us; speedup 1.0000x reference)
//
#include <hip/hip_runtime.h>
#include <cstdint>

#define TT 2048
#define DD 256
#define HH 8
#define LL 12

typedef __attribute__((ext_vector_type(8))) short s16x8;
typedef __attribute__((ext_vector_type(4))) float f32x4;

__device__ __forceinline__ unsigned short f2bf(float f) {
  union { float f; unsigned u; } v; v.f = f;
  return (unsigned short)((v.u + 0x7FFFu + ((v.u >> 16) & 1u)) >> 16);
}

__device__ __forceinline__ unsigned cvtpk(float lo, float hi) {
  unsigned r;
  asm("v_cvt_pk_bf16_f32 %0, %1, %2" : "=v"(r) : "v"(lo), "v"(hi));
  return r;
}

__device__ __forceinline__ float geluf(float x) {
  return 0.5f * x * (1.0f + erff(x * 0.70710678118654752f));
}

__device__ __forceinline__ float fexp2(float x) {
  float r;
  asm("v_exp_f32 %0, %1" : "=v"(r) : "v"(x));
  return r;
}

__device__ __forceinline__ void gload16(const void* g, void* l) {
  __builtin_amdgcn_global_load_lds((const __attribute__((address_space(1))) unsigned int*)g,
                                   (__attribute__((address_space(3))) unsigned int*)l, 16, 0, 0);
}

// ---------------- embedding: h = tok[x] + pos ----------------
__global__ __launch_bounds__(256) void k_embed(const int* __restrict__ x,
                                               const float* __restrict__ tok,
                                               const float* __restrict__ pos,
                                               float* __restrict__ h) {
  int i = blockIdx.x * 256 + threadIdx.x;
  int row = i >> 6, c = i & 63;
  int t = x[row];
  f32x4 tv = ((const f32x4*)(tok + (size_t)t * DD))[c];
  f32x4 pv = ((const f32x4*)(pos + (size_t)(row & (TT - 1)) * DD))[c];
  ((f32x4*)(h + (size_t)row * DD))[c] = tv + pv;
}

// ---------------- layernorm (f32 in) -> bf16 out (layer-0 ln1 only) ----------------
__global__ __launch_bounds__(256) void k_ln(const float* __restrict__ h,
                                            const float* __restrict__ wgt,
                                            const float* __restrict__ bia,
                                            unsigned short* __restrict__ z) {
  int row = blockIdx.x * 4 + (threadIdx.x >> 6);
  int lane = threadIdx.x & 63;
  f32x4 v = ((const f32x4*)(h + (size_t)row * DD))[lane];
  float s = v[0] + v[1] + v[2] + v[3];
#pragma unroll
  for (int m = 32; m; m >>= 1) s += __shfl_xor(s, m);
  float mean = s * (1.0f / DD);
  f32x4 d = v - mean;
  float s2 = d[0] * d[0] + d[1] * d[1] + d[2] * d[2] + d[3] * d[3];
#pragma unroll
  for (int m = 32; m; m >>= 1) s2 += __shfl_xor(s2, m);
  float inv = rsqrtf(s2 * (1.0f / DD) + 1e-5f);
  f32x4 wv = ((const f32x4*)wgt)[lane];
  f32x4 bv = ((const f32x4*)bia)[lane];
  float o0 = d[0] * inv * wv[0] + bv[0], o1 = d[1] * inv * wv[1] + bv[1];
  float o2 = d[2] * inv * wv[2] + bv[2], o3 = d[3] * inv * wv[3] + bv[3];
  unsigned long long u64 = (unsigned long long)cvtpk(o0, o1) |
                           ((unsigned long long)cvtpk(o2, o3) << 32);
  *(unsigned long long*)(z + (size_t)row * DD + lane * 4) = u64;
}

// ---------------- weight transpose-cast: LDS 32x32 tiles, all layers ----------------
__global__ __launch_bounds__(256) void k_cast_all(const float* __restrict__ qw, const float* __restrict__ ow,
                                                  const float* __restrict__ f1, const float* __restrict__ f2,
                                                  unsigned short* __restrict__ dst) {
  __shared__ float Tt[32][33];
  const int l = blockIdx.y;
  const int t = blockIdx.x;
  const float* src;
  unsigned short* d;
  int K, N, tk, tn;
  if (t < 192) {
    src = qw + (size_t)l * 196608; d = dst + (size_t)l * 786432;
    K = 256; N = 768; tk = t / 24; tn = t % 24;
  } else if (t < 256) {
    int t2 = t - 192;
    src = ow + (size_t)l * 65536; d = dst + (size_t)l * 786432 + 196608;
    K = 256; N = 256; tk = t2 >> 3; tn = t2 & 7;
  } else if (t < 512) {
    int t3 = t - 256;
    src = f1 + (size_t)l * 262144; d = dst + (size_t)l * 786432 + 262144;
    K = 256; N = 1024; tk = t3 >> 5; tn = t3 & 31;
  } else {
    int t4 = t - 512;
    src = f2 + (size_t)l * 262144; d = dst + (size_t)l * 786432 + 524288;
    K = 1024; N = 256; tk = t4 >> 3; tn = t4 & 7;
  }
  const int tx = threadIdx.x & 31, ty = threadIdx.x >> 5;
#pragma unroll
  for (int r = 0; r < 4; ++r) {
    int row = ty + r * 8;
    Tt[row][tx] = src[(size_t)(tk * 32 + row) * N + tn * 32 + tx];
  }
  __syncthreads();
#pragma unroll
  for (int r = 0; r < 4; ++r) {
    int row = ty + r * 8;
    d[(size_t)(tn * 32 + row) * K + tk * 32 + tx] = f2bf(Tt[tx][row]);
  }
}

// per-layer fallback (small ws)
__global__ __launch_bounds__(256) void k_cast_tr4(const float* __restrict__ qw, const float* __restrict__ ow,
                                                  const float* __restrict__ f1, const float* __restrict__ f2,
                                                  unsigned short* __restrict__ dq, unsigned short* __restrict__ dO,
                                                  unsigned short* __restrict__ d1, unsigned short* __restrict__ d2) {
  int t0 = blockIdx.x * 256 + threadIdx.x;
  int stride = gridDim.x * 256;
  for (int i = t0; i < 196608; i += stride) dq[i] = f2bf(qw[(i & 255) * 768 + (i >> 8)]);
  for (int i = t0; i < 65536; i += stride) dO[i] = f2bf(ow[(i & 255) * 256 + (i >> 8)]);
  for (int i = t0; i < 262144; i += stride) d1[i] = f2bf(f1[(i & 255) * 1024 + (i >> 8)]);
  for (int i = t0; i < 262144; i += stride) d2[i] = f2bf(f2[(i & 1023) * 256 + (i >> 10)]);
}

__global__ __launch_bounds__(256) void k_cast_tr256(const float* __restrict__ src, unsigned short* __restrict__ dst) {
  int i = blockIdx.x * 256 + threadIdx.x;
  dst[i] = f2bf(src[(i & 255) * 256 + (i >> 8)]);
}

// ---------------- GEMM v2: 2-phase double-buffered pipeline ----------------
template <int MODE, int MI>
__global__ __launch_bounds__(256, 3) void k_gemm(const unsigned short* __restrict__ A,
                                                 const unsigned short* __restrict__ BT,
                                                 const float* __restrict__ bias,
                                                 void* out, const float* resid,
                                                 int M, int N, int K) {
  __shared__ __align__(16) unsigned short As[2][MI * 32 * 64];
  __shared__ __align__(16) unsigned short Bs[2][128 * 64];
  const int tid = threadIdx.x;
  const int lane = tid & 63, wv = tid >> 6;
  const int wr = wv >> 1, wc = wv & 1;
  const int l15 = lane & 15, g = lane >> 4;
  const int BM = MI * 32;
  const int tm = blockIdx.y, tn = blockIdx.x;
  f32x4 acc[MI][4] = {};
  const int nk = K >> 6;
  const unsigned short* Ag0 = A + (size_t)tm * BM * K;
  const unsigned short* Bg0 = BT + (size_t)tn * 128 * K;

#pragma unroll
  for (int it = 0; it < MI; ++it) {
    int c = it * 256 + tid;
    gload16(Ag0 + (size_t)(c >> 3) * K + (c & 7) * 8, As[0] + c * 8);
  }
#pragma unroll
  for (int it = 0; it < 4; ++it) {
    int c = it * 256 + tid;
    gload16(Bg0 + (size_t)(c >> 3) * K + (c & 7) * 8, Bs[0] + c * 8);
  }
  __syncthreads();

  int buf = 0;
  for (int kt = 0; kt < nk; ++kt) {
    const bool have_next = (kt + 1 < nk);
    if (have_next) {
#pragma unroll
      for (int it = 0; it < MI; ++it) {
        int c = it * 256 + tid;
        gload16(Ag0 + (size_t)(c >> 3) * K + (kt + 1) * 64 + (c & 7) * 8, As[buf ^ 1] + c * 8);
      }
#pragma unroll
      for (int it = 0; it < 4; ++it) {
        int c = it * 256 + tid;
        gload16(Bg0 + (size_t)(c >> 3) * K + (kt + 1) * 64 + (c & 7) * 8, Bs[buf ^ 1] + c * 8);
      }
    }
#pragma unroll
    for (int ks = 0; ks < 2; ++ks) {
      s16x8 af[MI], bf[4];
#pragma unroll
      for (int mi = 0; mi < MI; ++mi)
        af[mi] = *(const s16x8*)(As[buf] + (wr * MI * 16 + mi * 16 + l15) * 64 + ks * 32 + g * 8);
#pragma unroll
      for (int ni = 0; ni < 4; ++ni)
        bf[ni] = *(const s16x8*)(Bs[buf] + (wc * 64 + ni * 16 + l15) * 64 + ks * 32 + g * 8);
#pragma unroll
      for (int mi = 0; mi < MI; ++mi)
#pragma unroll
        for (int ni = 0; ni < 4; ++ni)
          acc[mi][ni] = __builtin_amdgcn_mfma_f32_16x16x32_bf16(af[mi], bf[ni], acc[mi][ni], 0, 0, 0);
    }
    if (have_next) {
      __syncthreads();
      buf ^= 1;
    }
  }
#pragma unroll
  for (int ni = 0; ni < 4; ++ni) {
    int col = tn * 128 + wc * 64 + ni * 16 + l15;
    float bv = bias[col];
#pragma unroll
    for (int mi = 0; mi < MI; ++mi) {
      int row0 = tm * BM + wr * MI * 16 + mi * 16 + g * 4;
#pragma unroll
      for (int r = 0; r < 4; ++r) {
        size_t idx = (size_t)(row0 + r) * N + col;
        float vvv = acc[mi][ni][r] + bv;
        if (MODE == 0) ((unsigned short*)out)[idx] = f2bf(vvv);
        else if (MODE == 1) ((unsigned short*)out)[idx] = f2bf(geluf(vvv));
        else ((float*)out)[idx] = vvv;
      }
    }
  }
}

// ---------------- fused GEMM + residual + LayerNorm ----------------
template <int NK>
__global__ __launch_bounds__(256, 2) void k_gemm_ln(const unsigned short* __restrict__ A,
                                                    const unsigned short* __restrict__ BT,
                                                    const float* __restrict__ bias,
                                                    float* __restrict__ h,
                                                    const float* __restrict__ lnw,
                                                    const float* __restrict__ lnb,
                                                    unsigned short* __restrict__ z) {
  __shared__ __align__(16) unsigned short As[2][32 * 64];
  __shared__ __align__(16) unsigned short Bs[2][256 * 64];
  const int tid = threadIdx.x;
  const int lane = tid & 63, wc = tid >> 6;
  const int l15 = lane & 15, g = lane >> 4;
  const int tm = blockIdx.x;
  const int K = NK * 64;
  f32x4 acc[2][4] = {};
  const unsigned short* Ag0 = A + (size_t)tm * 32 * K;

  gload16(Ag0 + (size_t)(tid >> 3) * K + (tid & 7) * 8, As[0] + tid * 8);
#pragma unroll
  for (int it = 0; it < 8; ++it) {
    int c = it * 256 + tid;
    gload16(BT + (size_t)(c >> 3) * K + (c & 7) * 8, Bs[0] + c * 8);
  }
  __syncthreads();

  int buf = 0;
  for (int kt = 0; kt < NK; ++kt) {
    const bool have_next = (kt + 1 < NK);
    if (have_next) {
      gload16(Ag0 + (size_t)(tid >> 3) * K + (kt + 1) * 64 + (tid & 7) * 8, As[buf ^ 1] + tid * 8);
#pragma unroll
      for (int it = 0; it < 8; ++it) {
        int c = it * 256 + tid;
        gload16(BT + (size_t)(c >> 3) * K + (kt + 1) * 64 + (c & 7) * 8, Bs[buf ^ 1] + c * 8);
      }
    }
#pragma unroll
    for (int ks = 0; ks < 2; ++ks) {
      s16x8 af[2], bf[4];
#pragma unroll
      for (int mi = 0; mi < 2; ++mi)
        af[mi] = *(const s16x8*)(As[buf] + (mi * 16 + l15) * 64 + ks * 32 + g * 8);
#pragma unroll
      for (int ni = 0; ni < 4; ++ni)
        bf[ni] = *(const s16x8*)(Bs[buf] + (wc * 64 + ni * 16 + l15) * 64 + ks * 32 + g * 8);
#pragma unroll
      for (int mi = 0; mi < 2; ++mi)
#pragma unroll
        for (int ni = 0; ni < 4; ++ni)
          acc[mi][ni] = __builtin_amdgcn_mfma_f32_16x16x32_bf16(af[mi], bf[ni], acc[mi][ni], 0, 0, 0);
    }
    if (have_next) {
      __syncthreads();
      buf ^= 1;
    }
  }
  const int row0 = tm * 32;
  float hv[2][4][4];
  float psum[2][4] = {}, psq[2][4] = {};
#pragma unroll
  for (int mi = 0; mi < 2; ++mi)
#pragma unroll
    for (int ni = 0; ni < 4; ++ni) {
      int col = wc * 64 + ni * 16 + l15;
      float bv = bias[col];
#pragma unroll
      for (int r = 0; r < 4; ++r) {
        int row = row0 + mi * 16 + g * 4 + r;
        float v = acc[mi][ni][r] + bv + h[(size_t)row * DD + col];
        hv[mi][ni][r] = v;
        h[(size_t)row * DD + col] = v;
        psum[mi][r] += v;
        psq[mi][r] += v * v;
      }
    }
#pragma unroll
  for (int m = 1; m < 16; m <<= 1)
#pragma unroll
    for (int mi = 0; mi < 2; ++mi)
#pragma unroll
      for (int r = 0; r < 4; ++r) {
        psum[mi][r] += __shfl_xor(psum[mi][r], m);
        psq[mi][r] += __shfl_xor(psq[mi][r], m);
      }
  __syncthreads();
  float* red = (float*)&As[0][0];
  if (l15 == 0) {
#pragma unroll
    for (int mi = 0; mi < 2; ++mi)
#pragma unroll
      for (int r = 0; r < 4; ++r) {
        int rw = mi * 16 + g * 4 + r;
        red[wc * 32 + rw] = psum[mi][r];
        red[128 + wc * 32 + rw] = psq[mi][r];
      }
  }
  __syncthreads();
  float mean[2][4], inv[2][4];
#pragma unroll
  for (int mi = 0; mi < 2; ++mi)
#pragma unroll
    for (int r = 0; r < 4; ++r) {
      int rw = mi * 16 + g * 4 + r;
      float s = (red[rw] + red[32 + rw]) + (red[64 + rw] + red[96 + rw]);
      float q = (red[128 + rw] + red[160 + rw]) + (red[192 + rw] + red[224 + rw]);
      float mn = s * (1.0f / DD);
      mean[mi][r] = mn;
      inv[mi][r] = rsqrtf(q * (1.0f / DD) - mn * mn + 1e-5f);
    }
#pragma unroll
  for (int ni = 0; ni < 4; ++ni) {
    int col = wc * 64 + ni * 16 + l15;
    float wv = lnw[col], bv = lnb[col];
#pragma unroll
    for (int mi = 0; mi < 2; ++mi)
#pragma unroll
      for (int r = 0; r < 4; ++r) {
        int row = row0 + mi * 16 + g * 4 + r;
        z[(size_t)row * DD + col] = f2bf((hv[mi][ni][r] - mean[mi][r]) * inv[mi][r] * wv + bv);
      }
  }
}

// ---------------- fused causal flash attention v9: 32-row q-tiles, 4-way key split ----------------
// 1024 blocks (32 pairs x 32 bh) x 8 waves = 8192 waves = 32/CU (100%).
// Wave (w, kq): q-group w (16 rows), key-quarter kq (32 keys of each 128-key tile).
// Own online (m,l,O); 4-way flash-combine at the two phase ends via consumed buf.
// P slice aliased into wave's own staging region of buf^1 (stride 40, conflict-free).
__global__ __launch_bounds__(512, 8) void k_attn(const unsigned short* __restrict__ qkv,
                                                 unsigned short* __restrict__ o) {
  __shared__ __align__(16) unsigned short Ks[2][128 * 40];
  __shared__ __align__(16) unsigned short Vs[2][2 * 32 * 72];
  const int tid = threadIdx.x, lane = tid & 63, wvi = tid >> 6;
  const int w = wvi >> 2, kq = wvi & 3;
  const int l15 = lane & 15, g = lane >> 4;
  const int p = blockIdx.x;  // 0..31
  const int b = blockIdx.y >> 3, hh = blockIdx.y & 7;
  const size_t base = (size_t)b * TT * 768 + hh * 32;
  const float scl2 = 0.25503492f;  // (1/sqrt(32)) * log2(e)
  const int qt0 = p, qt1 = 63 - p;
  const int nt0 = (qt0 >> 2) + 1;
  // staging roles: waves 0-3 stage K rows [32*wvi, +32); waves 4-7 stage V slice wvi-4
  const int krow = (wvi & 3) * 32 + (lane >> 1);
  const int khK = lane & 1;
  const int iv = wvi & 3;
  const int khv = iv >> 1, dh = iv & 1;

  s16x8 qf0 = *(const s16x8*)(qkv + base + (size_t)(qt0 * 32 + w * 16 + l15) * 768 + g * 8);
  s16x8 qf1 = *(const s16x8*)(qkv + base + (size_t)(qt1 * 32 + w * 16 + l15) * 768 + g * 8);

  // prologue: stage tile 0 into buf 0
  if (wvi < 4) {
    const unsigned short* kp = qkv + base + (size_t)krow * 768 + 256 + khK * 16;
    s16x8 k0 = *(const s16x8*)kp;
    s16x8 k1 = *(const s16x8*)(kp + 8);
    *(s16x8*)(Ks[0] + krow * 40 + khK * 16) = k0;
    *(s16x8*)(Ks[0] + krow * 40 + khK * 16 + 8) = k1;
  } else {
    const unsigned short* vp = qkv + base + (size_t)(khv * 64 + lane) * 768 + 512 + dh * 16;
    s16x8 v0 = *(const s16x8*)vp;
    s16x8 v1 = *(const s16x8*)(vp + 8);
    unsigned short* vb = Vs[0] + khv * 2304;
#pragma unroll
    for (int e = 0; e < 8; ++e) {
      int d0 = dh * 16 + e, d1 = dh * 16 + 8 + e;
      vb[d0 * 72 + (lane ^ (((d0 >> 3) & 3) << 4))] = (unsigned short)v0[e];
      vb[d1 * 72 + (lane ^ (((d1 >> 3) & 3) << 4))] = (unsigned short)v1[e];
    }
  }
  __syncthreads();

  f32x4 accO[2] = {};
  float mM = -3.0e38f, ls = 0.f;

  for (int t = 0; t < 17; ++t) {
    const int buf = t & 1;
    const bool ph = (t >= nt0);
    const int qt = ph ? qt1 : qt0;
    const int j = ph ? t - nt0 : t;
    const bool have_next = (t + 1 < 17);
    unsigned short* ps = (wvi < 4) ? (Ks[buf ^ 1] + wvi * 1280)
                                   : (Vs[buf ^ 1] + (wvi - 4) * 1152);
    s16x8 k0n, k1n, v0n, v1n;
    if (have_next) {
      const int jn = (t + 1 >= nt0) ? t + 1 - nt0 : t + 1;
      if (wvi < 4) {
        const unsigned short* kp = qkv + base + (size_t)(jn * 128 + krow) * 768 + 256 + khK * 16;
        k0n = *(const s16x8*)kp;
        k1n = *(const s16x8*)(kp + 8);
      } else {
        const unsigned short* vp = qkv + base + (size_t)(jn * 128 + khv * 64 + lane) * 768 + 512 + dh * 16;
        v0n = *(const s16x8*)vp;
        v1n = *(const s16x8*)(vp + 8);
      }
    }
    // ---- compute: wave handles local cb c in {0,1}; global cb = kq*2 + c ----
    const int rel = qt * 32 + w * 16 - j * 128;  // wave-uniform, >= 0
    int cbg = (rel + 15) >> 4; if (cbg > 7) cbg = 7;
    const int cbm = (cbg - kq * 2 > 1) ? 1 : cbg - kq * 2;  // may be < 0
    if (cbm >= 0) {
      const bool fullw = (rel >= kq * 32 + 31);
      f32x4 st[2];
#pragma unroll
      for (int c = 0; c < 2; ++c)
        if (c <= cbm) {
          s16x8 kf = *(const s16x8*)(Ks[buf] + (kq * 32 + c * 16 + l15) * 40 + g * 8);
          f32x4 zz = {};
          st[c] = __builtin_amdgcn_mfma_f32_16x16x32_bf16(kf, ph ? qf1 : qf0, zz, 0, 0, 0);
        }
      float rmax = -3.0e38f;
#pragma unroll
      for (int c = 0; c < 2; ++c)
        if (c <= cbm) {
          if (!fullw) {
#pragma unroll
            for (int r = 0; r < 4; ++r)
              if ((kq * 32 + c * 16 + g * 4 + r) > rel + l15) st[c][r] = -3.0e38f;
          }
#pragma unroll
          for (int r = 0; r < 4; ++r) rmax = fmaxf(rmax, st[c][r]);
        }
      rmax = fmaxf(rmax, __shfl_xor(rmax, 16));
      rmax = fmaxf(rmax, __shfl_xor(rmax, 32));
      const float rs = rmax * scl2;
      float al = 1.0f;
      if (!__all(rs <= mM + 11.5f)) {
        float nm = fmaxf(mM, rs);
        al = fexp2(mM - nm);
        mM = nm;
#pragma unroll
        for (int r = 0; r < 4; ++r) {
          float aw = __shfl(al, g * 4 + r);
          accO[0][r] *= aw;
          accO[1][r] *= aw;
        }
      }
      float rsum = 0.f;
#pragma unroll
      for (int c = 0; c < 2; ++c)
        if (c <= cbm) {
          float e0 = fexp2(fmaf(st[c][0], scl2, -mM));
          float e1 = fexp2(fmaf(st[c][1], scl2, -mM));
          float e2 = fexp2(fmaf(st[c][2], scl2, -mM));
          float e3 = fexp2(fmaf(st[c][3], scl2, -mM));
          rsum += (e0 + e1) + (e2 + e3);
          unsigned long long u = (unsigned long long)cvtpk(e0, e1) |
                                 ((unsigned long long)cvtpk(e2, e3) << 32);
          *(unsigned long long*)(ps + l15 * 40 + c * 16 + g * 4) = u;
        }
      if (cbm < 1)
        *(unsigned long long*)(ps + l15 * 40 + 16 + g * 4) = 0ULL;
      rsum += __shfl_xor(rsum, 16);
      rsum += __shfl_xor(rsum, 32);
      ls = ls * al + rsum;
      asm volatile("s_waitcnt lgkmcnt(0)" ::: "memory");
      __builtin_amdgcn_sched_barrier(0);
      // PV: single K=32 step over this wave's key quarter
      {
        s16x8 pa = *(const s16x8*)(ps + l15 * 40 + g * 8);
        s16x8 bv0, bv1;
#pragma unroll
        for (int hb = 0; hb < 2; ++hb) {
          const int d = hb * 16 + l15;
          const int kx = ((kq & 1) * 32 + g * 8) ^ (((d >> 3) & 3) << 4);
          if (hb == 0) bv0 = *(const s16x8*)(Vs[buf] + (kq >> 1) * 2304 + d * 72 + kx);
          else bv1 = *(const s16x8*)(Vs[buf] + (kq >> 1) * 2304 + d * 72 + kx);
        }
        accO[0] = __builtin_amdgcn_mfma_f32_16x16x32_bf16(pa, bv0, accO[0], 0, 0, 0);
        accO[1] = __builtin_amdgcn_mfma_f32_16x16x32_bf16(pa, bv1, accO[1], 0, 0, 0);
      }
    }
    // ---- stage next tile into buf^1 (own region), then barrier ----
    if (have_next) {
      if (wvi < 4) {
        *(s16x8*)(Ks[buf ^ 1] + krow * 40 + khK * 16) = k0n;
        *(s16x8*)(Ks[buf ^ 1] + krow * 40 + khK * 16 + 8) = k1n;
      } else {
        unsigned short* vb = Vs[buf ^ 1] + khv * 2304;
#pragma unroll
        for (int e = 0; e < 8; ++e) {
          int d0 = dh * 16 + e, d1 = dh * 16 + 8 + e;
          vb[d0 * 72 + (lane ^ (((d0 >> 3) & 3) << 4))] = (unsigned short)v0n[e];
          vb[d1 * 72 + (lane ^ (((d1 >> 3) & 3) << 4))] = (unsigned short)v1n[e];
        }
      }
      __syncthreads();
    }
    // ---- phase-0 boundary: 4-way flash-combine, write O(qt0), reset ----
    if (t == nt0 - 1) {
      float* sc = (float*)((wvi < 4) ? (Ks[buf] + wvi * 1280) : (Vs[buf] + (wvi - 4) * 1152));
#pragma unroll
      for (int hb = 0; hb < 2; ++hb)
#pragma unroll
        for (int r = 0; r < 4; ++r) sc[(g * 4 + r) * 32 + hb * 16 + l15] = accO[hb][r];
      if (g == 0) { sc[512 + l15] = mM; sc[528 + l15] = ls; }
      __syncthreads();
      if (kq == 0) {
        const float* pb1 = (const float*)((wvi + 1 < 4) ? (Ks[buf] + (wvi + 1) * 1280) : (Vs[buf] + (wvi - 3) * 1152));
        const float* pb2 = (const float*)((wvi + 2 < 4) ? (Ks[buf] + (wvi + 2) * 1280) : (Vs[buf] + (wvi - 2) * 1152));
        const float* pb3 = (const float*)((wvi + 3 < 4) ? (Ks[buf] + (wvi + 3) * 1280) : (Vs[buf] + (wvi - 1) * 1152));
#pragma unroll
        for (int r = 0; r < 4; ++r) {
          int q = g * 4 + r;
          float m0 = __shfl(mM, q), l0 = __shfl(ls, q);
          float m1 = pb1[512 + q], l1 = pb1[528 + q];
          float m2 = pb2[512 + q], l2 = pb2[528 + q];
          float m3 = pb3[512 + q], l3 = pb3[528 + q];
          float M = fmaxf(fmaxf(m0, m1), fmaxf(m2, m3));
          float e0 = fexp2(m0 - M), e1 = fexp2(m1 - M), e2 = fexp2(m2 - M), e3 = fexp2(m3 - M);
          float inv = 1.0f / (e0 * l0 + e1 * l1 + e2 * l2 + e3 * l3);
          int row = qt0 * 32 + w * 16 + q;
#pragma unroll
          for (int hb = 0; hb < 2; ++hb) {
            int oi = q * 32 + hb * 16 + l15;
            float val = e0 * accO[hb][r] + e1 * pb1[oi] + e2 * pb2[oi] + e3 * pb3[oi];
            o[(size_t)(b * TT + row) * DD + hh * 32 + hb * 16 + l15] = f2bf(val * inv);
          }
        }
      }
      __syncthreads();
      accO[0] = f32x4{};
      accO[1] = f32x4{};
      mM = -3.0e38f;
      ls = 0.f;
    }
  }
  // ---- final 4-way combine for qt1 (buf of t=16 is 0) ----
  {
    __syncthreads();
    float* sc = (float*)((wvi < 4) ? (Ks[0] + wvi * 1280) : (Vs[0] + (wvi - 4) * 1152));
#pragma unroll
    for (int hb = 0; hb < 2; ++hb)
#pragma unroll
      for (int r = 0; r < 4; ++r) sc[(g * 4 + r) * 32 + hb * 16 + l15] = accO[hb][r];
    if (g == 0) { sc[512 + l15] = mM; sc[528 + l15] = ls; }
    __syncthreads();
    if (kq == 0) {
      const float* pb1 = (const float*)((wvi + 1 < 4) ? (Ks[0] + (wvi + 1) * 1280) : (Vs[0] + (wvi - 3) * 1152));
      const float* pb2 = (const float*)((wvi + 2 < 4) ? (Ks[0] + (wvi + 2) * 1280) : (Vs[0] + (wvi - 2) * 1152));
      const float* pb3 = (const float*)((wvi + 3 < 4) ? (Ks[0] + (wvi + 3) * 1280) : (Vs[0] + (wvi - 1) * 1152));
#pragma unroll
      for (int r = 0; r < 4; ++r) {
        int q = g * 4 + r;
        float m0 = __shfl(mM, q), l0 = __shfl(ls, q);
        float m1 = pb1[512 + q], l1 = pb1[528 + q];
        float m2 = pb2[512 + q], l2 = pb2[528 + q];
        float m3 = pb3[512 + q], l3 = pb3[528 + q];
        float M = fmaxf(fmaxf(m0, m1), fmaxf(m2, m3));
        float e0 = fexp2(m0 - M), e1 = fexp2(m1 - M), e2 = fexp2(m2 - M), e3 = fexp2(m3 - M);
        float inv = 1.0f / (e0 * l0 + e1 * l1 + e2 * l2 + e3 * l3);
        int row = qt1 * 32 + w * 16 + q;
#pragma unroll
        for (int hb = 0; hb < 2; ++hb) {
          int oi = q * 32 + hb * 16 + l15;
          float val = e0 * accO[hb][r] + e1 * pb1[oi] + e2 * pb2[oi] + e3 * pb3[oi];
          o[(size_t)(b * TT + row) * DD + hh * 32 + hb * 16 + l15] = f2bf(val * inv);
        }
      }
    }
  }
}

extern "C" void kernel_launch(void* const* d_in, const int* in_sizes, int n_in,
                              void* d_out, int out_size, void* d_ws, size_t ws_size,
                              hipStream_t stream) {
  const int* x = (const int*)d_in[0];
  const float* tok = (const float*)d_in[1];
  const float* pos = (const float*)d_in[2];
  const float* ln1w = (const float*)d_in[3];
  const float* ln1b = (const float*)d_in[4];
  const float* qkvw = (const float*)d_in[5];
  const float* qkvb = (const float*)d_in[6];
  const float* outw = (const float*)d_in[7];
  const float* outb = (const float*)d_in[8];
  const float* ln2w = (const float*)d_in[9];
  const float* ln2b = (const float*)d_in[10];
  const float* f1w = (const float*)d_in[11];
  const float* f1b = (const float*)d_in[12];
  const float* f2w = (const float*)d_in[13];
  const float* f2b = (const float*)d_in[14];
  const float* lnfw = (const float*)d_in[15];
  const float* lnfb = (const float*)d_in[16];
  const float* hw = (const float*)d_in[17];
  const float* hb = (const float*)d_in[18];

  char* ws = (char*)d_ws;
  float* h = (float*)(ws + 0);                              //  8 MB
  unsigned short* z = (unsigned short*)(ws + 8388608);      //  4 MB
  unsigned short* qkvB = (unsigned short*)(ws + 12582912);  // 12 MB
  unsigned short* ob = (unsigned short*)(ws + 25165824);    //  4 MB
  unsigned short* a1 = (unsigned short*)(ws + 29360128);    // 16 MB
  unsigned short* wAll = (unsigned short*)(ws + 46137344);  // 18 MB (12 layers) or 1.5 MB (fallback)
  const bool bigws = ws_size >= 65142784ULL;
  unsigned short* wh = (unsigned short*)(ws + (bigws ? 65011712 : 47710208));

  if (bigws)
    k_cast_all<<<dim3(768, 12), dim3(256), 0, stream>>>(qkvw, outw, f1w, f2w, wAll);
  k_cast_tr256<<<dim3(256), dim3(256), 0, stream>>>(hw, wh);
  k_embed<<<dim3(2048), dim3(256), 0, stream>>>(x, tok, pos, h);
  k_ln<<<dim3(2048), dim3(256), 0, stream>>>(h, ln1w, ln1b, z);  // layer-0 ln1

  for (int l = 0; l < LL; ++l) {
    unsigned short* wq = wAll + (size_t)(bigws ? l : 0) * 786432;
    unsigned short* wo = wq + 196608;
    unsigned short* w1 = wo + 65536;
    unsigned short* w2 = w1 + 262144;
    if (!bigws)
      k_cast_tr4<<<dim3(1024), dim3(256), 0, stream>>>(
          qkvw + (size_t)l * 196608, outw + (size_t)l * 65536,
          f1w + (size_t)l * 262144, f2w + (size_t)l * 262144, wq, wo, w1, w2);
    k_gemm<0, 2><<<dim3(6, 128), dim3(256), 0, stream>>>(z, wq, qkvb + l * 768, qkvB, nullptr, 8192, 768, 256);
    k_attn<<<dim3(32, 32), dim3(512), 0, stream>>>(qkvB, ob);
    k_gemm_ln<4><<<dim3(256), dim3(256), 0, stream>>>(ob, wo, outb + l * 256, h,
                                                      ln2w + l * 256, ln2b + l * 256, z);
    k_gemm<1, 2><<<dim3(8, 128), dim3(256), 0, stream>>>(z, w1, f1b + l * 1024, a1, nullptr, 8192, 1024, 256);
    const float* nw = (l == LL - 1) ? lnfw : ln1w + (l + 1) * 256;
    const float* nb = (l == LL - 1) ? lnfb : ln1b + (l + 1) * 256;
    k_gemm_ln<16><<<dim3(256), dim3(256), 0, stream>>>(a1, w2, f2b + l * 256, h, nw, nb, z);
  }

  k_gemm<3, 2><<<dim3(2, 128), dim3(256), 0, stream>>>(z, wh, hb, d_out, nullptr, 8192, 256, 256);
}

// Round 14
// 1470.595 us; speedup vs baseline: 2.8118x; 2.8118x over previous
//
#include <hip/hip_runtime.h>
#include <cstdint>

#define TT 2048
#define DD 256
#define HH 8
#define LL 12

typedef __attribute__((ext_vector_type(8))) short s16x8;
typedef __attribute__((ext_vector_type(4))) float f32x4;

__device__ __forceinline__ unsigned short f2bf(float f) {
  union { float f; unsigned u; } v; v.f = f;
  return (unsigned short)((v.u + 0x7FFFu + ((v.u >> 16) & 1u)) >> 16);
}

__device__ __forceinline__ unsigned cvtpk(float lo, float hi) {
  unsigned r;
  asm("v_cvt_pk_bf16_f32 %0, %1, %2" : "=v"(r) : "v"(lo), "v"(hi));
  return r;
}

__device__ __forceinline__ float geluf(float x) {
  return 0.5f * x * (1.0f + erff(x * 0.70710678118654752f));
}

__device__ __forceinline__ float fexp2(float x) {
  float r;
  asm("v_exp_f32 %0, %1" : "=v"(r) : "v"(x));
  return r;
}

__device__ __forceinline__ void gload16(const void* g, void* l) {
  __builtin_amdgcn_global_load_lds((const __attribute__((address_space(1))) unsigned int*)g,
                                   (__attribute__((address_space(3))) unsigned int*)l, 16, 0, 0);
}

// ---------------- embedding: h = tok[x] + pos ----------------
__global__ __launch_bounds__(256) void k_embed(const int* __restrict__ x,
                                               const float* __restrict__ tok,
                                               const float* __restrict__ pos,
                                               float* __restrict__ h) {
  int i = blockIdx.x * 256 + threadIdx.x;
  int row = i >> 6, c = i & 63;
  int t = x[row];
  f32x4 tv = ((const f32x4*)(tok + (size_t)t * DD))[c];
  f32x4 pv = ((const f32x4*)(pos + (size_t)(row & (TT - 1)) * DD))[c];
  ((f32x4*)(h + (size_t)row * DD))[c] = tv + pv;
}

// ---------------- layernorm (f32 in) -> bf16 out (layer-0 ln1 only) ----------------
__global__ __launch_bounds__(256) void k_ln(const float* __restrict__ h,
                                            const float* __restrict__ wgt,
                                            const float* __restrict__ bia,
                                            unsigned short* __restrict__ z) {
  int row = blockIdx.x * 4 + (threadIdx.x >> 6);
  int lane = threadIdx.x & 63;
  f32x4 v = ((const f32x4*)(h + (size_t)row * DD))[lane];
  float s = v[0] + v[1] + v[2] + v[3];
#pragma unroll
  for (int m = 32; m; m >>= 1) s += __shfl_xor(s, m);
  float mean = s * (1.0f / DD);
  f32x4 d = v - mean;
  float s2 = d[0] * d[0] + d[1] * d[1] + d[2] * d[2] + d[3] * d[3];
#pragma unroll
  for (int m = 32; m; m >>= 1) s2 += __shfl_xor(s2, m);
  float inv = rsqrtf(s2 * (1.0f / DD) + 1e-5f);
  f32x4 wv = ((const f32x4*)wgt)[lane];
  f32x4 bv = ((const f32x4*)bia)[lane];
  float o0 = d[0] * inv * wv[0] + bv[0], o1 = d[1] * inv * wv[1] + bv[1];
  float o2 = d[2] * inv * wv[2] + bv[2], o3 = d[3] * inv * wv[3] + bv[3];
  unsigned long long u64 = (unsigned long long)cvtpk(o0, o1) |
                           ((unsigned long long)cvtpk(o2, o3) << 32);
  *(unsigned long long*)(z + (size_t)row * DD + lane * 4) = u64;
}

// ---------------- weight transpose-cast: LDS 32x32 tiles, all layers ----------------
__global__ __launch_bounds__(256) void k_cast_all(const float* __restrict__ qw, const float* __restrict__ ow,
                                                  const float* __restrict__ f1, const float* __restrict__ f2,
                                                  unsigned short* __restrict__ dst) {
  __shared__ float Tt[32][33];
  const int l = blockIdx.y;
  const int t = blockIdx.x;
  const float* src;
  unsigned short* d;
  int K, N, tk, tn;
  if (t < 192) {
    src = qw + (size_t)l * 196608; d = dst + (size_t)l * 786432;
    K = 256; N = 768; tk = t / 24; tn = t % 24;
  } else if (t < 256) {
    int t2 = t - 192;
    src = ow + (size_t)l * 65536; d = dst + (size_t)l * 786432 + 196608;
    K = 256; N = 256; tk = t2 >> 3; tn = t2 & 7;
  } else if (t < 512) {
    int t3 = t - 256;
    src = f1 + (size_t)l * 262144; d = dst + (size_t)l * 786432 + 262144;
    K = 256; N = 1024; tk = t3 >> 5; tn = t3 & 31;
  } else {
    int t4 = t - 512;
    src = f2 + (size_t)l * 262144; d = dst + (size_t)l * 786432 + 524288;
    K = 1024; N = 256; tk = t4 >> 3; tn = t4 & 7;
  }
  const int tx = threadIdx.x & 31, ty = threadIdx.x >> 5;
#pragma unroll
  for (int r = 0; r < 4; ++r) {
    int row = ty + r * 8;
    Tt[row][tx] = src[(size_t)(tk * 32 + row) * N + tn * 32 + tx];
  }
  __syncthreads();
#pragma unroll
  for (int r = 0; r < 4; ++r) {
    int row = ty + r * 8;
    d[(size_t)(tn * 32 + row) * K + tk * 32 + tx] = f2bf(Tt[tx][row]);
  }
}

// per-layer fallback (small ws)
__global__ __launch_bounds__(256) void k_cast_tr4(const float* __restrict__ qw, const float* __restrict__ ow,
                                                  const float* __restrict__ f1, const float* __restrict__ f2,
                                                  unsigned short* __restrict__ dq, unsigned short* __restrict__ dO,
                                                  unsigned short* __restrict__ d1, unsigned short* __restrict__ d2) {
  int t0 = blockIdx.x * 256 + threadIdx.x;
  int stride = gridDim.x * 256;
  for (int i = t0; i < 196608; i += stride) dq[i] = f2bf(qw[(i & 255) * 768 + (i >> 8)]);
  for (int i = t0; i < 65536; i += stride) dO[i] = f2bf(ow[(i & 255) * 256 + (i >> 8)]);
  for (int i = t0; i < 262144; i += stride) d1[i] = f2bf(f1[(i & 255) * 1024 + (i >> 8)]);
  for (int i = t0; i < 262144; i += stride) d2[i] = f2bf(f2[(i & 1023) * 256 + (i >> 10)]);
}

__global__ __launch_bounds__(256) void k_cast_tr256(const float* __restrict__ src, unsigned short* __restrict__ dst) {
  int i = blockIdx.x * 256 + threadIdx.x;
  dst[i] = f2bf(src[(i & 255) * 256 + (i >> 8)]);
}

// ---------------- GEMM v2: 2-phase double-buffered pipeline ----------------
template <int MODE, int MI>
__global__ __launch_bounds__(256, 3) void k_gemm(const unsigned short* __restrict__ A,
                                                 const unsigned short* __restrict__ BT,
                                                 const float* __restrict__ bias,
                                                 void* out, const float* resid,
                                                 int M, int N, int K) {
  __shared__ __align__(16) unsigned short As[2][MI * 32 * 64];
  __shared__ __align__(16) unsigned short Bs[2][128 * 64];
  const int tid = threadIdx.x;
  const int lane = tid & 63, wv = tid >> 6;
  const int wr = wv >> 1, wc = wv & 1;
  const int l15 = lane & 15, g = lane >> 4;
  const int BM = MI * 32;
  const int tm = blockIdx.y, tn = blockIdx.x;
  f32x4 acc[MI][4] = {};
  const int nk = K >> 6;
  const unsigned short* Ag0 = A + (size_t)tm * BM * K;
  const unsigned short* Bg0 = BT + (size_t)tn * 128 * K;

#pragma unroll
  for (int it = 0; it < MI; ++it) {
    int c = it * 256 + tid;
    gload16(Ag0 + (size_t)(c >> 3) * K + (c & 7) * 8, As[0] + c * 8);
  }
#pragma unroll
  for (int it = 0; it < 4; ++it) {
    int c = it * 256 + tid;
    gload16(Bg0 + (size_t)(c >> 3) * K + (c & 7) * 8, Bs[0] + c * 8);
  }
  __syncthreads();

  int buf = 0;
  for (int kt = 0; kt < nk; ++kt) {
    const bool have_next = (kt + 1 < nk);
    if (have_next) {
#pragma unroll
      for (int it = 0; it < MI; ++it) {
        int c = it * 256 + tid;
        gload16(Ag0 + (size_t)(c >> 3) * K + (kt + 1) * 64 + (c & 7) * 8, As[buf ^ 1] + c * 8);
      }
#pragma unroll
      for (int it = 0; it < 4; ++it) {
        int c = it * 256 + tid;
        gload16(Bg0 + (size_t)(c >> 3) * K + (kt + 1) * 64 + (c & 7) * 8, Bs[buf ^ 1] + c * 8);
      }
    }
#pragma unroll
    for (int ks = 0; ks < 2; ++ks) {
      s16x8 af[MI], bf[4];
#pragma unroll
      for (int mi = 0; mi < MI; ++mi)
        af[mi] = *(const s16x8*)(As[buf] + (wr * MI * 16 + mi * 16 + l15) * 64 + ks * 32 + g * 8);
#pragma unroll
      for (int ni = 0; ni < 4; ++ni)
        bf[ni] = *(const s16x8*)(Bs[buf] + (wc * 64 + ni * 16 + l15) * 64 + ks * 32 + g * 8);
#pragma unroll
      for (int mi = 0; mi < MI; ++mi)
#pragma unroll
        for (int ni = 0; ni < 4; ++ni)
          acc[mi][ni] = __builtin_amdgcn_mfma_f32_16x16x32_bf16(af[mi], bf[ni], acc[mi][ni], 0, 0, 0);
    }
    if (have_next) {
      __syncthreads();
      buf ^= 1;
    }
  }
#pragma unroll
  for (int ni = 0; ni < 4; ++ni) {
    int col = tn * 128 + wc * 64 + ni * 16 + l15;
    float bv = bias[col];
#pragma unroll
    for (int mi = 0; mi < MI; ++mi) {
      int row0 = tm * BM + wr * MI * 16 + mi * 16 + g * 4;
#pragma unroll
      for (int r = 0; r < 4; ++r) {
        size_t idx = (size_t)(row0 + r) * N + col;
        float vvv = acc[mi][ni][r] + bv;
        if (MODE == 0) ((unsigned short*)out)[idx] = f2bf(vvv);
        else if (MODE == 1) ((unsigned short*)out)[idx] = f2bf(geluf(vvv));
        else ((float*)out)[idx] = vvv;
      }
    }
  }
}

// ---------------- fused GEMM + residual + LayerNorm ----------------
template <int NK>
__global__ __launch_bounds__(256, 2) void k_gemm_ln(const unsigned short* __restrict__ A,
                                                    const unsigned short* __restrict__ BT,
                                                    const float* __restrict__ bias,
                                                    float* __restrict__ h,
                                                    const float* __restrict__ lnw,
                                                    const float* __restrict__ lnb,
                                                    unsigned short* __restrict__ z) {
  __shared__ __align__(16) unsigned short As[2][32 * 64];
  __shared__ __align__(16) unsigned short Bs[2][256 * 64];
  const int tid = threadIdx.x;
  const int lane = tid & 63, wc = tid >> 6;
  const int l15 = lane & 15, g = lane >> 4;
  const int tm = blockIdx.x;
  const int K = NK * 64;
  f32x4 acc[2][4] = {};
  const unsigned short* Ag0 = A + (size_t)tm * 32 * K;

  gload16(Ag0 + (size_t)(tid >> 3) * K + (tid & 7) * 8, As[0] + tid * 8);
#pragma unroll
  for (int it = 0; it < 8; ++it) {
    int c = it * 256 + tid;
    gload16(BT + (size_t)(c >> 3) * K + (c & 7) * 8, Bs[0] + c * 8);
  }
  __syncthreads();

  int buf = 0;
  for (int kt = 0; kt < NK; ++kt) {
    const bool have_next = (kt + 1 < NK);
    if (have_next) {
      gload16(Ag0 + (size_t)(tid >> 3) * K + (kt + 1) * 64 + (tid & 7) * 8, As[buf ^ 1] + tid * 8);
#pragma unroll
      for (int it = 0; it < 8; ++it) {
        int c = it * 256 + tid;
        gload16(BT + (size_t)(c >> 3) * K + (kt + 1) * 64 + (c & 7) * 8, Bs[buf ^ 1] + c * 8);
      }
    }
#pragma unroll
    for (int ks = 0; ks < 2; ++ks) {
      s16x8 af[2], bf[4];
#pragma unroll
      for (int mi = 0; mi < 2; ++mi)
        af[mi] = *(const s16x8*)(As[buf] + (mi * 16 + l15) * 64 + ks * 32 + g * 8);
#pragma unroll
      for (int ni = 0; ni < 4; ++ni)
        bf[ni] = *(const s16x8*)(Bs[buf] + (wc * 64 + ni * 16 + l15) * 64 + ks * 32 + g * 8);
#pragma unroll
      for (int mi = 0; mi < 2; ++mi)
#pragma unroll
        for (int ni = 0; ni < 4; ++ni)
          acc[mi][ni] = __builtin_amdgcn_mfma_f32_16x16x32_bf16(af[mi], bf[ni], acc[mi][ni], 0, 0, 0);
    }
    if (have_next) {
      __syncthreads();
      buf ^= 1;
    }
  }
  const int row0 = tm * 32;
  float hv[2][4][4];
  float psum[2][4] = {}, psq[2][4] = {};
#pragma unroll
  for (int mi = 0; mi < 2; ++mi)
#pragma unroll
    for (int ni = 0; ni < 4; ++ni) {
      int col = wc * 64 + ni * 16 + l15;
      float bv = bias[col];
#pragma unroll
      for (int r = 0; r < 4; ++r) {
        int row = row0 + mi * 16 + g * 4 + r;
        float v = acc[mi][ni][r] + bv + h[(size_t)row * DD + col];
        hv[mi][ni][r] = v;
        h[(size_t)row * DD + col] = v;
        psum[mi][r] += v;
        psq[mi][r] += v * v;
      }
    }
#pragma unroll
  for (int m = 1; m < 16; m <<= 1)
#pragma unroll
    for (int mi = 0; mi < 2; ++mi)
#pragma unroll
      for (int r = 0; r < 4; ++r) {
        psum[mi][r] += __shfl_xor(psum[mi][r], m);
        psq[mi][r] += __shfl_xor(psq[mi][r], m);
      }
  __syncthreads();
  float* red = (float*)&As[0][0];
  if (l15 == 0) {
#pragma unroll
    for (int mi = 0; mi < 2; ++mi)
#pragma unroll
      for (int r = 0; r < 4; ++r) {
        int rw = mi * 16 + g * 4 + r;
        red[wc * 32 + rw] = psum[mi][r];
        red[128 + wc * 32 + rw] = psq[mi][r];
      }
  }
  __syncthreads();
  float mean[2][4], inv[2][4];
#pragma unroll
  for (int mi = 0; mi < 2; ++mi)
#pragma unroll
    for (int r = 0; r < 4; ++r) {
      int rw = mi * 16 + g * 4 + r;
      float s = (red[rw] + red[32 + rw]) + (red[64 + rw] + red[96 + rw]);
      float q = (red[128 + rw] + red[160 + rw]) + (red[192 + rw] + red[224 + rw]);
      float mn = s * (1.0f / DD);
      mean[mi][r] = mn;
      inv[mi][r] = rsqrtf(q * (1.0f / DD) - mn * mn + 1e-5f);
    }
#pragma unroll
  for (int ni = 0; ni < 4; ++ni) {
    int col = wc * 64 + ni * 16 + l15;
    float wv = lnw[col], bv = lnb[col];
#pragma unroll
    for (int mi = 0; mi < 2; ++mi)
#pragma unroll
      for (int r = 0; r < 4; ++r) {
        int row = row0 + mi * 16 + g * 4 + r;
        z[(size_t)row * DD + col] = f2bf((hv[mi][ni][r] - mean[mi][r]) * inv[mi][r] * wv + bv);
      }
  }
}

// ---------------- fused causal flash attention v9.1: 32-row q-tiles, 4-way key split ----------------
// 1024 blocks (32 pairs x 32 bh) x 8 waves; launch_bounds(512,4) -> VGPR<=128 (v13's
// (512,8) forced 64-cap -> scratch spill, 1.2GB/dispatch). Expect ~64 VGPR -> 4 blk/CU.
__global__ __launch_bounds__(512, 4) void k_attn(const unsigned short* __restrict__ qkv,
                                                 unsigned short* __restrict__ o) {
  __shared__ __align__(16) unsigned short Ks[2][128 * 40];
  __shared__ __align__(16) unsigned short Vs[2][2 * 32 * 72];
  const int tid = threadIdx.x, lane = tid & 63, wvi = tid >> 6;
  const int w = wvi >> 2, kq = wvi & 3;
  const int l15 = lane & 15, g = lane >> 4;
  const int p = blockIdx.x;  // 0..31
  const int b = blockIdx.y >> 3, hh = blockIdx.y & 7;
  const size_t base = (size_t)b * TT * 768 + hh * 32;
  const float scl2 = 0.25503492f;  // (1/sqrt(32)) * log2(e)
  const int qt0 = p, qt1 = 63 - p;
  const int nt0 = (qt0 >> 2) + 1;
  const int krow = (wvi & 3) * 32 + (lane >> 1);
  const int khK = lane & 1;
  const int iv = wvi & 3;
  const int khv = iv >> 1, dh = iv & 1;

  s16x8 qf0 = *(const s16x8*)(qkv + base + (size_t)(qt0 * 32 + w * 16 + l15) * 768 + g * 8);
  s16x8 qf1 = *(const s16x8*)(qkv + base + (size_t)(qt1 * 32 + w * 16 + l15) * 768 + g * 8);

  if (wvi < 4) {
    const unsigned short* kp = qkv + base + (size_t)krow * 768 + 256 + khK * 16;
    s16x8 k0 = *(const s16x8*)kp;
    s16x8 k1 = *(const s16x8*)(kp + 8);
    *(s16x8*)(Ks[0] + krow * 40 + khK * 16) = k0;
    *(s16x8*)(Ks[0] + krow * 40 + khK * 16 + 8) = k1;
  } else {
    const unsigned short* vp = qkv + base + (size_t)(khv * 64 + lane) * 768 + 512 + dh * 16;
    s16x8 v0 = *(const s16x8*)vp;
    s16x8 v1 = *(const s16x8*)(vp + 8);
    unsigned short* vb = Vs[0] + khv * 2304;
#pragma unroll
    for (int e = 0; e < 8; ++e) {
      int d0 = dh * 16 + e, d1 = dh * 16 + 8 + e;
      vb[d0 * 72 + (lane ^ (((d0 >> 3) & 3) << 4))] = (unsigned short)v0[e];
      vb[d1 * 72 + (lane ^ (((d1 >> 3) & 3) << 4))] = (unsigned short)v1[e];
    }
  }
  __syncthreads();

  f32x4 accO[2] = {};
  float mM = -3.0e38f, ls = 0.f;

  for (int t = 0; t < 17; ++t) {
    const int buf = t & 1;
    const bool ph = (t >= nt0);
    const int qt = ph ? qt1 : qt0;
    const int j = ph ? t - nt0 : t;
    const bool have_next = (t + 1 < 17);
    unsigned short* ps = (wvi < 4) ? (Ks[buf ^ 1] + wvi * 1280)
                                   : (Vs[buf ^ 1] + (wvi - 4) * 1152);
    s16x8 k0n, k1n, v0n, v1n;
    if (have_next) {
      const int jn = (t + 1 >= nt0) ? t + 1 - nt0 : t + 1;
      if (wvi < 4) {
        const unsigned short* kp = qkv + base + (size_t)(jn * 128 + krow) * 768 + 256 + khK * 16;
        k0n = *(const s16x8*)kp;
        k1n = *(const s16x8*)(kp + 8);
      } else {
        const unsigned short* vp = qkv + base + (size_t)(jn * 128 + khv * 64 + lane) * 768 + 512 + dh * 16;
        v0n = *(const s16x8*)vp;
        v1n = *(const s16x8*)(vp + 8);
      }
    }
    const int rel = qt * 32 + w * 16 - j * 128;
    int cbg = (rel + 15) >> 4; if (cbg > 7) cbg = 7;
    const int cbm = (cbg - kq * 2 > 1) ? 1 : cbg - kq * 2;
    if (cbm >= 0) {
      const bool fullw = (rel >= kq * 32 + 31);
      f32x4 st[2];
#pragma unroll
      for (int c = 0; c < 2; ++c)
        if (c <= cbm) {
          s16x8 kf = *(const s16x8*)(Ks[buf] + (kq * 32 + c * 16 + l15) * 40 + g * 8);
          f32x4 zz = {};
          st[c] = __builtin_amdgcn_mfma_f32_16x16x32_bf16(kf, ph ? qf1 : qf0, zz, 0, 0, 0);
        }
      float rmax = -3.0e38f;
#pragma unroll
      for (int c = 0; c < 2; ++c)
        if (c <= cbm) {
          if (!fullw) {
#pragma unroll
            for (int r = 0; r < 4; ++r)
              if ((kq * 32 + c * 16 + g * 4 + r) > rel + l15) st[c][r] = -3.0e38f;
          }
#pragma unroll
          for (int r = 0; r < 4; ++r) rmax = fmaxf(rmax, st[c][r]);
        }
      rmax = fmaxf(rmax, __shfl_xor(rmax, 16));
      rmax = fmaxf(rmax, __shfl_xor(rmax, 32));
      const float rs = rmax * scl2;
      float al = 1.0f;
      if (!__all(rs <= mM + 11.5f)) {
        float nm = fmaxf(mM, rs);
        al = fexp2(mM - nm);
        mM = nm;
#pragma unroll
        for (int r = 0; r < 4; ++r) {
          float aw = __shfl(al, g * 4 + r);
          accO[0][r] *= aw;
          accO[1][r] *= aw;
        }
      }
      float rsum = 0.f;
#pragma unroll
      for (int c = 0; c < 2; ++c)
        if (c <= cbm) {
          float e0 = fexp2(fmaf(st[c][0], scl2, -mM));
          float e1 = fexp2(fmaf(st[c][1], scl2, -mM));
          float e2 = fexp2(fmaf(st[c][2], scl2, -mM));
          float e3 = fexp2(fmaf(st[c][3], scl2, -mM));
          rsum += (e0 + e1) + (e2 + e3);
          unsigned long long u = (unsigned long long)cvtpk(e0, e1) |
                                 ((unsigned long long)cvtpk(e2, e3) << 32);
          *(unsigned long long*)(ps + l15 * 40 + c * 16 + g * 4) = u;
        }
      if (cbm < 1)
        *(unsigned long long*)(ps + l15 * 40 + 16 + g * 4) = 0ULL;
      rsum += __shfl_xor(rsum, 16);
      rsum += __shfl_xor(rsum, 32);
      ls = ls * al + rsum;
      asm volatile("s_waitcnt lgkmcnt(0)" ::: "memory");
      __builtin_amdgcn_sched_barrier(0);
      {
        s16x8 pa = *(const s16x8*)(ps + l15 * 40 + g * 8);
        s16x8 bv0, bv1;
#pragma unroll
        for (int hb = 0; hb < 2; ++hb) {
          const int d = hb * 16 + l15;
          const int kx = ((kq & 1) * 32 + g * 8) ^ (((d >> 3) & 3) << 4);
          if (hb == 0) bv0 = *(const s16x8*)(Vs[buf] + (kq >> 1) * 2304 + d * 72 + kx);
          else bv1 = *(const s16x8*)(Vs[buf] + (kq >> 1) * 2304 + d * 72 + kx);
        }
        accO[0] = __builtin_amdgcn_mfma_f32_16x16x32_bf16(pa, bv0, accO[0], 0, 0, 0);
        accO[1] = __builtin_amdgcn_mfma_f32_16x16x32_bf16(pa, bv1, accO[1], 0, 0, 0);
      }
    }
    if (have_next) {
      if (wvi < 4) {
        *(s16x8*)(Ks[buf ^ 1] + krow * 40 + khK * 16) = k0n;
        *(s16x8*)(Ks[buf ^ 1] + krow * 40 + khK * 16 + 8) = k1n;
      } else {
        unsigned short* vb = Vs[buf ^ 1] + khv * 2304;
#pragma unroll
        for (int e = 0; e < 8; ++e) {
          int d0 = dh * 16 + e, d1 = dh * 16 + 8 + e;
          vb[d0 * 72 + (lane ^ (((d0 >> 3) & 3) << 4))] = (unsigned short)v0n[e];
          vb[d1 * 72 + (lane ^ (((d1 >> 3) & 3) << 4))] = (unsigned short)v1n[e];
        }
      }
      __syncthreads();
    }
    if (t == nt0 - 1) {
      float* sc = (float*)((wvi < 4) ? (Ks[buf] + wvi * 1280) : (Vs[buf] + (wvi - 4) * 1152));
#pragma unroll
      for (int hb = 0; hb < 2; ++hb)
#pragma unroll
        for (int r = 0; r < 4; ++r) sc[(g * 4 + r) * 32 + hb * 16 + l15] = accO[hb][r];
      if (g == 0) { sc[512 + l15] = mM; sc[528 + l15] = ls; }
      __syncthreads();
      if (kq == 0) {
        const float* pb1 = (const float*)((wvi + 1 < 4) ? (Ks[buf] + (wvi + 1) * 1280) : (Vs[buf] + (wvi - 3) * 1152));
        const float* pb2 = (const float*)((wvi + 2 < 4) ? (Ks[buf] + (wvi + 2) * 1280) : (Vs[buf] + (wvi - 2) * 1152));
        const float* pb3 = (const float*)((wvi + 3 < 4) ? (Ks[buf] + (wvi + 3) * 1280) : (Vs[buf] + (wvi - 1) * 1152));
#pragma unroll
        for (int r = 0; r < 4; ++r) {
          int q = g * 4 + r;
          float m0 = __shfl(mM, q), l0 = __shfl(ls, q);
          float m1 = pb1[512 + q], l1 = pb1[528 + q];
          float m2 = pb2[512 + q], l2 = pb2[528 + q];
          float m3 = pb3[512 + q], l3 = pb3[528 + q];
          float M = fmaxf(fmaxf(m0, m1), fmaxf(m2, m3));
          float e0 = fexp2(m0 - M), e1 = fexp2(m1 - M), e2 = fexp2(m2 - M), e3 = fexp2(m3 - M);
          float inv = 1.0f / (e0 * l0 + e1 * l1 + e2 * l2 + e3 * l3);
          int row = qt0 * 32 + w * 16 + q;
#pragma unroll
          for (int hb = 0; hb < 2; ++hb) {
            int oi = q * 32 + hb * 16 + l15;
            float val = e0 * accO[hb][r] + e1 * pb1[oi] + e2 * pb2[oi] + e3 * pb3[oi];
            o[(size_t)(b * TT + row) * DD + hh * 32 + hb * 16 + l15] = f2bf(val * inv);
          }
        }
      }
      __syncthreads();
      accO[0] = f32x4{};
      accO[1] = f32x4{};
      mM = -3.0e38f;
      ls = 0.f;
    }
  }
  {
    __syncthreads();
    float* sc = (float*)((wvi < 4) ? (Ks[0] + wvi * 1280) : (Vs[0] + (wvi - 4) * 1152));
#pragma unroll
    for (int hb = 0; hb < 2; ++hb)
#pragma unroll
      for (int r = 0; r < 4; ++r) sc[(g * 4 + r) * 32 + hb * 16 + l15] = accO[hb][r];
    if (g == 0) { sc[512 + l15] = mM; sc[528 + l15] = ls; }
    __syncthreads();
    if (kq == 0) {
      const float* pb1 = (const float*)((wvi + 1 < 4) ? (Ks[0] + (wvi + 1) * 1280) : (Vs[0] + (wvi - 3) * 1152));
      const float* pb2 = (const float*)((wvi + 2 < 4) ? (Ks[0] + (wvi + 2) * 1280) : (Vs[0] + (wvi - 2) * 1152));
      const float* pb3 = (const float*)((wvi + 3 < 4) ? (Ks[0] + (wvi + 3) * 1280) : (Vs[0] + (wvi - 1) * 1152));
#pragma unroll
      for (int r = 0; r < 4; ++r) {
        int q = g * 4 + r;
        float m0 = __shfl(mM, q), l0 = __shfl(ls, q);
        float m1 = pb1[512 + q], l1 = pb1[528 + q];
        float m2 = pb2[512 + q], l2 = pb2[528 + q];
        float m3 = pb3[512 + q], l3 = pb3[528 + q];
        float M = fmaxf(fmaxf(m0, m1), fmaxf(m2, m3));
        float e0 = fexp2(m0 - M), e1 = fexp2(m1 - M), e2 = fexp2(m2 - M), e3 = fexp2(m3 - M);
        float inv = 1.0f / (e0 * l0 + e1 * l1 + e2 * l2 + e3 * l3);
        int row = qt1 * 32 + w * 16 + q;
#pragma unroll
        for (int hb = 0; hb < 2; ++hb) {
          int oi = q * 32 + hb * 16 + l15;
          float val = e0 * accO[hb][r] + e1 * pb1[oi] + e2 * pb2[oi] + e3 * pb3[oi];
          o[(size_t)(b * TT + row) * DD + hh * 32 + hb * 16 + l15] = f2bf(val * inv);
        }
      }
    }
  }
}

extern "C" void kernel_launch(void* const* d_in, const int* in_sizes, int n_in,
                              void* d_out, int out_size, void* d_ws, size_t ws_size,
                              hipStream_t stream) {
  const int* x = (const int*)d_in[0];
  const float* tok = (const float*)d_in[1];
  const float* pos = (const float*)d_in[2];
  const float* ln1w = (const float*)d_in[3];
  const float* ln1b = (const float*)d_in[4];
  const float* qkvw = (const float*)d_in[5];
  const float* qkvb = (const float*)d_in[6];
  const float* outw = (const float*)d_in[7];
  const float* outb = (const float*)d_in[8];
  const float* ln2w = (const float*)d_in[9];
  const float* ln2b = (const float*)d_in[10];
  const float* f1w = (const float*)d_in[11];
  const float* f1b = (const float*)d_in[12];
  const float* f2w = (const float*)d_in[13];
  const float* f2b = (const float*)d_in[14];
  const float* lnfw = (const float*)d_in[15];
  const float* lnfb = (const float*)d_in[16];
  const float* hw = (const float*)d_in[17];
  const float* hb = (const float*)d_in[18];

  char* ws = (char*)d_ws;
  float* h = (float*)(ws + 0);                              //  8 MB
  unsigned short* z = (unsigned short*)(ws + 8388608);      //  4 MB
  unsigned short* qkvB = (unsigned short*)(ws + 12582912);  // 12 MB
  unsigned short* ob = (unsigned short*)(ws + 25165824);    //  4 MB
  unsigned short* a1 = (unsigned short*)(ws + 29360128);    // 16 MB
  unsigned short* wAll = (unsigned short*)(ws + 46137344);  // 18 MB (12 layers) or 1.5 MB (fallback)
  const bool bigws = ws_size >= 65142784ULL;
  unsigned short* wh = (unsigned short*)(ws + (bigws ? 65011712 : 47710208));

  if (bigws)
    k_cast_all<<<dim3(768, 12), dim3(256), 0, stream>>>(qkvw, outw, f1w, f2w, wAll);
  k_cast_tr256<<<dim3(256), dim3(256), 0, stream>>>(hw, wh);
  k_embed<<<dim3(2048), dim3(256), 0, stream>>>(x, tok, pos, h);
  k_ln<<<dim3(2048), dim3(256), 0, stream>>>(h, ln1w, ln1b, z);  // layer-0 ln1

  for (int l = 0; l < LL; ++l) {
    unsigned short* wq = wAll + (size_t)(bigws ? l : 0) * 786432;
    unsigned short* wo = wq + 196608;
    unsigned short* w1 = wo + 65536;
    unsigned short* w2 = w1 + 262144;
    if (!bigws)
      k_cast_tr4<<<dim3(1024), dim3(256), 0, stream>>>(
          qkvw + (size_t)l * 196608, outw + (size_t)l * 65536,
          f1w + (size_t)l * 262144, f2w + (size_t)l * 262144, wq, wo, w1, w2);
    k_gemm<0, 2><<<dim3(6, 128), dim3(256), 0, stream>>>(z, wq, qkvb + l * 768, qkvB, nullptr, 8192, 768, 256);
    k_attn<<<dim3(32, 32), dim3(512), 0, stream>>>(qkvB, ob);
    k_gemm_ln<4><<<dim3(256), dim3(256), 0, stream>>>(ob, wo, outb + l * 256, h,
                                                      ln2w + l * 256, ln2b + l * 256, z);
    k_gemm<1, 2><<<dim3(8, 128), dim3(256), 0, stream>>>(z, w1, f1b + l * 1024, a1, nullptr, 8192, 1024, 256);
    const float* nw = (l == LL - 1) ? lnfw : ln1w + (l + 1) * 256;
    const float* nb = (l == LL - 1) ? lnfb : ln1b + (l + 1) * 256;
    k_gemm_ln<16><<<dim3(256), dim3(256), 0, stream>>>(a1, w2, f2b + l * 256, h, nw, nb, z);
  }

  k_gemm<3, 2><<<dim3(2, 128), dim3(256), 0, stream>>>(z, wh, hb, d_out, nullptr, 8192, 256, 256);
}

// Round 15
// 1283.410 us; speedup vs baseline: 3.2219x; 1.1458x over previous
//
#include <hip/hip_runtime.h>
#include <cstdint>

#define TT 2048
#define DD 256
#define HH 8
#define LL 12

typedef __attribute__((ext_vector_type(8))) short s16x8;
typedef __attribute__((ext_vector_type(4))) float f32x4;

__device__ __forceinline__ unsigned short f2bf(float f) {
  union { float f; unsigned u; } v; v.f = f;
  return (unsigned short)((v.u + 0x7FFFu + ((v.u >> 16) & 1u)) >> 16);
}

__device__ __forceinline__ unsigned cvtpk(float lo, float hi) {
  unsigned r;
  asm("v_cvt_pk_bf16_f32 %0, %1, %2" : "=v"(r) : "v"(lo), "v"(hi));
  return r;
}

__device__ __forceinline__ float geluf(float x) {
  return 0.5f * x * (1.0f + erff(x * 0.70710678118654752f));
}

__device__ __forceinline__ float fexp2(float x) {
  float r;
  asm("v_exp_f32 %0, %1" : "=v"(r) : "v"(x));
  return r;
}

__device__ __forceinline__ void gload16(const void* g, void* l) {
  __builtin_amdgcn_global_load_lds((const __attribute__((address_space(1))) unsigned int*)g,
                                   (__attribute__((address_space(3))) unsigned int*)l, 16, 0, 0);
}

// ---------------- embedding: h = tok[x] + pos ----------------
__global__ __launch_bounds__(256) void k_embed(const int* __restrict__ x,
                                               const float* __restrict__ tok,
                                               const float* __restrict__ pos,
                                               float* __restrict__ h) {
  int i = blockIdx.x * 256 + threadIdx.x;
  int row = i >> 6, c = i & 63;
  int t = x[row];
  f32x4 tv = ((const f32x4*)(tok + (size_t)t * DD))[c];
  f32x4 pv = ((const f32x4*)(pos + (size_t)(row & (TT - 1)) * DD))[c];
  ((f32x4*)(h + (size_t)row * DD))[c] = tv + pv;
}

// ---------------- layernorm (f32 in) -> bf16 out (layer-0 ln1 only) ----------------
__global__ __launch_bounds__(256) void k_ln(const float* __restrict__ h,
                                            const float* __restrict__ wgt,
                                            const float* __restrict__ bia,
                                            unsigned short* __restrict__ z) {
  int row = blockIdx.x * 4 + (threadIdx.x >> 6);
  int lane = threadIdx.x & 63;
  f32x4 v = ((const f32x4*)(h + (size_t)row * DD))[lane];
  float s = v[0] + v[1] + v[2] + v[3];
#pragma unroll
  for (int m = 32; m; m >>= 1) s += __shfl_xor(s, m);
  float mean = s * (1.0f / DD);
  f32x4 d = v - mean;
  float s2 = d[0] * d[0] + d[1] * d[1] + d[2] * d[2] + d[3] * d[3];
#pragma unroll
  for (int m = 32; m; m >>= 1) s2 += __shfl_xor(s2, m);
  float inv = rsqrtf(s2 * (1.0f / DD) + 1e-5f);
  f32x4 wv = ((const f32x4*)wgt)[lane];
  f32x4 bv = ((const f32x4*)bia)[lane];
  float o0 = d[0] * inv * wv[0] + bv[0], o1 = d[1] * inv * wv[1] + bv[1];
  float o2 = d[2] * inv * wv[2] + bv[2], o3 = d[3] * inv * wv[3] + bv[3];
  unsigned long long u64 = (unsigned long long)cvtpk(o0, o1) |
                           ((unsigned long long)cvtpk(o2, o3) << 32);
  *(unsigned long long*)(z + (size_t)row * DD + lane * 4) = u64;
}

// ---------------- weight transpose-cast: LDS 32x32 tiles, all layers ----------------
__global__ __launch_bounds__(256) void k_cast_all(const float* __restrict__ qw, const float* __restrict__ ow,
                                                  const float* __restrict__ f1, const float* __restrict__ f2,
                                                  unsigned short* __restrict__ dst) {
  __shared__ float Tt[32][33];
  const int l = blockIdx.y;
  const int t = blockIdx.x;
  const float* src;
  unsigned short* d;
  int K, N, tk, tn;
  if (t < 192) {
    src = qw + (size_t)l * 196608; d = dst + (size_t)l * 786432;
    K = 256; N = 768; tk = t / 24; tn = t % 24;
  } else if (t < 256) {
    int t2 = t - 192;
    src = ow + (size_t)l * 65536; d = dst + (size_t)l * 786432 + 196608;
    K = 256; N = 256; tk = t2 >> 3; tn = t2 & 7;
  } else if (t < 512) {
    int t3 = t - 256;
    src = f1 + (size_t)l * 262144; d = dst + (size_t)l * 786432 + 262144;
    K = 256; N = 1024; tk = t3 >> 5; tn = t3 & 31;
  } else {
    int t4 = t - 512;
    src = f2 + (size_t)l * 262144; d = dst + (size_t)l * 786432 + 524288;
    K = 1024; N = 256; tk = t4 >> 3; tn = t4 & 7;
  }
  const int tx = threadIdx.x & 31, ty = threadIdx.x >> 5;
#pragma unroll
  for (int r = 0; r < 4; ++r) {
    int row = ty + r * 8;
    Tt[row][tx] = src[(size_t)(tk * 32 + row) * N + tn * 32 + tx];
  }
  __syncthreads();
#pragma unroll
  for (int r = 0; r < 4; ++r) {
    int row = ty + r * 8;
    d[(size_t)(tn * 32 + row) * K + tk * 32 + tx] = f2bf(Tt[tx][row]);
  }
}

// per-layer fallback (small ws)
__global__ __launch_bounds__(256) void k_cast_tr4(const float* __restrict__ qw, const float* __restrict__ ow,
                                                  const float* __restrict__ f1, const float* __restrict__ f2,
                                                  unsigned short* __restrict__ dq, unsigned short* __restrict__ dO,
                                                  unsigned short* __restrict__ d1, unsigned short* __restrict__ d2) {
  int t0 = blockIdx.x * 256 + threadIdx.x;
  int stride = gridDim.x * 256;
  for (int i = t0; i < 196608; i += stride) dq[i] = f2bf(qw[(i & 255) * 768 + (i >> 8)]);
  for (int i = t0; i < 65536; i += stride) dO[i] = f2bf(ow[(i & 255) * 256 + (i >> 8)]);
  for (int i = t0; i < 262144; i += stride) d1[i] = f2bf(f1[(i & 255) * 1024 + (i >> 8)]);
  for (int i = t0; i < 262144; i += stride) d2[i] = f2bf(f2[(i & 1023) * 256 + (i >> 10)]);
}

__global__ __launch_bounds__(256) void k_cast_tr256(const float* __restrict__ src, unsigned short* __restrict__ dst) {
  int i = blockIdx.x * 256 + threadIdx.x;
  dst[i] = f2bf(src[(i & 255) * 256 + (i >> 8)]);
}

// ---------------- GEMM v2: 2-phase double-buffered pipeline ----------------
template <int MODE, int MI>
__global__ __launch_bounds__(256, 3) void k_gemm(const unsigned short* __restrict__ A,
                                                 const unsigned short* __restrict__ BT,
                                                 const float* __restrict__ bias,
                                                 void* out, const float* resid,
                                                 int M, int N, int K) {
  __shared__ __align__(16) unsigned short As[2][MI * 32 * 64];
  __shared__ __align__(16) unsigned short Bs[2][128 * 64];
  const int tid = threadIdx.x;
  const int lane = tid & 63, wv = tid >> 6;
  const int wr = wv >> 1, wc = wv & 1;
  const int l15 = lane & 15, g = lane >> 4;
  const int BM = MI * 32;
  const int tm = blockIdx.y, tn = blockIdx.x;
  f32x4 acc[MI][4] = {};
  const int nk = K >> 6;
  const unsigned short* Ag0 = A + (size_t)tm * BM * K;
  const unsigned short* Bg0 = BT + (size_t)tn * 128 * K;

#pragma unroll
  for (int it = 0; it < MI; ++it) {
    int c = it * 256 + tid;
    gload16(Ag0 + (size_t)(c >> 3) * K + (c & 7) * 8, As[0] + c * 8);
  }
#pragma unroll
  for (int it = 0; it < 4; ++it) {
    int c = it * 256 + tid;
    gload16(Bg0 + (size_t)(c >> 3) * K + (c & 7) * 8, Bs[0] + c * 8);
  }
  __syncthreads();

  int buf = 0;
  for (int kt = 0; kt < nk; ++kt) {
    const bool have_next = (kt + 1 < nk);
    if (have_next) {
#pragma unroll
      for (int it = 0; it < MI; ++it) {
        int c = it * 256 + tid;
        gload16(Ag0 + (size_t)(c >> 3) * K + (kt + 1) * 64 + (c & 7) * 8, As[buf ^ 1] + c * 8);
      }
#pragma unroll
      for (int it = 0; it < 4; ++it) {
        int c = it * 256 + tid;
        gload16(Bg0 + (size_t)(c >> 3) * K + (kt + 1) * 64 + (c & 7) * 8, Bs[buf ^ 1] + c * 8);
      }
    }
#pragma unroll
    for (int ks = 0; ks < 2; ++ks) {
      s16x8 af[MI], bf[4];
#pragma unroll
      for (int mi = 0; mi < MI; ++mi)
        af[mi] = *(const s16x8*)(As[buf] + (wr * MI * 16 + mi * 16 + l15) * 64 + ks * 32 + g * 8);
#pragma unroll
      for (int ni = 0; ni < 4; ++ni)
        bf[ni] = *(const s16x8*)(Bs[buf] + (wc * 64 + ni * 16 + l15) * 64 + ks * 32 + g * 8);
#pragma unroll
      for (int mi = 0; mi < MI; ++mi)
#pragma unroll
        for (int ni = 0; ni < 4; ++ni)
          acc[mi][ni] = __builtin_amdgcn_mfma_f32_16x16x32_bf16(af[mi], bf[ni], acc[mi][ni], 0, 0, 0);
    }
    if (have_next) {
      __syncthreads();
      buf ^= 1;
    }
  }
#pragma unroll
  for (int ni = 0; ni < 4; ++ni) {
    int col = tn * 128 + wc * 64 + ni * 16 + l15;
    float bv = bias[col];
#pragma unroll
    for (int mi = 0; mi < MI; ++mi) {
      int row0 = tm * BM + wr * MI * 16 + mi * 16 + g * 4;
#pragma unroll
      for (int r = 0; r < 4; ++r) {
        size_t idx = (size_t)(row0 + r) * N + col;
        float vvv = acc[mi][ni][r] + bv;
        if (MODE == 0) ((unsigned short*)out)[idx] = f2bf(vvv);
        else if (MODE == 1) ((unsigned short*)out)[idx] = f2bf(geluf(vvv));
        else ((float*)out)[idx] = vvv;
      }
    }
  }
}

// ---------------- fused GEMM + residual + LayerNorm ----------------
template <int NK>
__global__ __launch_bounds__(256, 2) void k_gemm_ln(const unsigned short* __restrict__ A,
                                                    const unsigned short* __restrict__ BT,
                                                    const float* __restrict__ bias,
                                                    float* __restrict__ h,
                                                    const float* __restrict__ lnw,
                                                    const float* __restrict__ lnb,
                                                    unsigned short* __restrict__ z) {
  __shared__ __align__(16) unsigned short As[2][32 * 64];
  __shared__ __align__(16) unsigned short Bs[2][256 * 64];
  const int tid = threadIdx.x;
  const int lane = tid & 63, wc = tid >> 6;
  const int l15 = lane & 15, g = lane >> 4;
  const int tm = blockIdx.x;
  const int K = NK * 64;
  f32x4 acc[2][4] = {};
  const unsigned short* Ag0 = A + (size_t)tm * 32 * K;

  gload16(Ag0 + (size_t)(tid >> 3) * K + (tid & 7) * 8, As[0] + tid * 8);
#pragma unroll
  for (int it = 0; it < 8; ++it) {
    int c = it * 256 + tid;
    gload16(BT + (size_t)(c >> 3) * K + (c & 7) * 8, Bs[0] + c * 8);
  }
  __syncthreads();

  int buf = 0;
  for (int kt = 0; kt < NK; ++kt) {
    const bool have_next = (kt + 1 < NK);
    if (have_next) {
      gload16(Ag0 + (size_t)(tid >> 3) * K + (kt + 1) * 64 + (tid & 7) * 8, As[buf ^ 1] + tid * 8);
#pragma unroll
      for (int it = 0; it < 8; ++it) {
        int c = it * 256 + tid;
        gload16(BT + (size_t)(c >> 3) * K + (kt + 1) * 64 + (c & 7) * 8, Bs[buf ^ 1] + c * 8);
      }
    }
#pragma unroll
    for (int ks = 0; ks < 2; ++ks) {
      s16x8 af[2], bf[4];
#pragma unroll
      for (int mi = 0; mi < 2; ++mi)
        af[mi] = *(const s16x8*)(As[buf] + (mi * 16 + l15) * 64 + ks * 32 + g * 8);
#pragma unroll
      for (int ni = 0; ni < 4; ++ni)
        bf[ni] = *(const s16x8*)(Bs[buf] + (wc * 64 + ni * 16 + l15) * 64 + ks * 32 + g * 8);
#pragma unroll
      for (int mi = 0; mi < 2; ++mi)
#pragma unroll
        for (int ni = 0; ni < 4; ++ni)
          acc[mi][ni] = __builtin_amdgcn_mfma_f32_16x16x32_bf16(af[mi], bf[ni], acc[mi][ni], 0, 0, 0);
    }
    if (have_next) {
      __syncthreads();
      buf ^= 1;
    }
  }
  const int row0 = tm * 32;
  float hv[2][4][4];
  float psum[2][4] = {}, psq[2][4] = {};
#pragma unroll
  for (int mi = 0; mi < 2; ++mi)
#pragma unroll
    for (int ni = 0; ni < 4; ++ni) {
      int col = wc * 64 + ni * 16 + l15;
      float bv = bias[col];
#pragma unroll
      for (int r = 0; r < 4; ++r) {
        int row = row0 + mi * 16 + g * 4 + r;
        float v = acc[mi][ni][r] + bv + h[(size_t)row * DD + col];
        hv[mi][ni][r] = v;
        h[(size_t)row * DD + col] = v;
        psum[mi][r] += v;
        psq[mi][r] += v * v;
      }
    }
#pragma unroll
  for (int m = 1; m < 16; m <<= 1)
#pragma unroll
    for (int mi = 0; mi < 2; ++mi)
#pragma unroll
      for (int r = 0; r < 4; ++r) {
        psum[mi][r] += __shfl_xor(psum[mi][r], m);
        psq[mi][r] += __shfl_xor(psq[mi][r], m);
      }
  __syncthreads();
  float* red = (float*)&As[0][0];
  if (l15 == 0) {
#pragma unroll
    for (int mi = 0; mi < 2; ++mi)
#pragma unroll
      for (int r = 0; r < 4; ++r) {
        int rw = mi * 16 + g * 4 + r;
        red[wc * 32 + rw] = psum[mi][r];
        red[128 + wc * 32 + rw] = psq[mi][r];
      }
  }
  __syncthreads();
  float mean[2][4], inv[2][4];
#pragma unroll
  for (int mi = 0; mi < 2; ++mi)
#pragma unroll
    for (int r = 0; r < 4; ++r) {
      int rw = mi * 16 + g * 4 + r;
      float s = (red[rw] + red[32 + rw]) + (red[64 + rw] + red[96 + rw]);
      float q = (red[128 + rw] + red[160 + rw]) + (red[192 + rw] + red[224 + rw]);
      float mn = s * (1.0f / DD);
      mean[mi][r] = mn;
      inv[mi][r] = rsqrtf(q * (1.0f / DD) - mn * mn + 1e-5f);
    }
#pragma unroll
  for (int ni = 0; ni < 4; ++ni) {
    int col = wc * 64 + ni * 16 + l15;
    float wv = lnw[col], bv = lnb[col];
#pragma unroll
    for (int mi = 0; mi < 2; ++mi)
#pragma unroll
      for (int r = 0; r < 4; ++r) {
        int row = row0 + mi * 16 + g * 4 + r;
        z[(size_t)row * DD + col] = f2bf((hv[mi][ni][r] - mean[mi][r]) * inv[mi][r] * wv + bv);
      }
  }
}

// ---------------- fused causal flash attention v8 (round-12 best: 48 us) ----------------
// 512 blocks (16 pairs x 32 bh), 512 threads = 8 waves = 4 q-groups x 2 key-halves.
// Wave (w,kh) handles keys [kh*64, kh*64+64) of each 128-key tile with its own
// online (m,l,O); halves flash-combine at the two phase ends via consumed LDS buf.
__global__ __launch_bounds__(512, 4) void k_attn(const unsigned short* __restrict__ qkv,
                                                 unsigned short* __restrict__ o) {
  __shared__ __align__(16) unsigned short Ks[2][128 * 40];
  __shared__ __align__(16) unsigned short Vs[2][2 * 32 * 72];
  const int tid = threadIdx.x, lane = tid & 63, wvi = tid >> 6;
  const int w = wvi >> 1, kh = wvi & 1;
  const int l15 = lane & 15, g = lane >> 4;
  const int p = blockIdx.x;  // 0..15
  const int b = blockIdx.y >> 3, hh = blockIdx.y & 7;
  const size_t base = (size_t)b * TT * 768 + hh * 32;
  const float scl2 = 0.25503492f;  // (1/sqrt(32)) * log2(e)
  const int qt0 = p, qt1 = 31 - p;
  const int nt0 = (qt0 >> 1) + 1;
  const int krow = (wvi & 3) * 32 + (lane >> 1);
  const int khK = lane & 1;
  const int iv = wvi & 3;
  const int khv = iv >> 1, dh = iv & 1;

  s16x8 qf0 = *(const s16x8*)(qkv + base + (size_t)(qt0 * 64 + w * 16 + l15) * 768 + g * 8);
  s16x8 qf1 = *(const s16x8*)(qkv + base + (size_t)(qt1 * 64 + w * 16 + l15) * 768 + g * 8);

  if (wvi < 4) {
    const unsigned short* kp = qkv + base + (size_t)krow * 768 + 256 + khK * 16;
    s16x8 k0 = *(const s16x8*)kp;
    s16x8 k1 = *(const s16x8*)(kp + 8);
    *(s16x8*)(Ks[0] + krow * 40 + khK * 16) = k0;
    *(s16x8*)(Ks[0] + krow * 40 + khK * 16 + 8) = k1;
  } else {
    const unsigned short* vp = qkv + base + (size_t)(khv * 64 + lane) * 768 + 512 + dh * 16;
    s16x8 v0 = *(const s16x8*)vp;
    s16x8 v1 = *(const s16x8*)(vp + 8);
    unsigned short* vb = Vs[0] + khv * 2304;
#pragma unroll
    for (int e = 0; e < 8; ++e) {
      int d0 = dh * 16 + e, d1 = dh * 16 + 8 + e;
      vb[d0 * 72 + (lane ^ (((d0 >> 3) & 3) << 4))] = (unsigned short)v0[e];
      vb[d1 * 72 + (lane ^ (((d1 >> 3) & 3) << 4))] = (unsigned short)v1[e];
    }
  }
  __syncthreads();

  f32x4 accO[2] = {};
  float mM = -3.0e38f, ls = 0.f;

  for (int t = 0; t < 17; ++t) {
    const int buf = t & 1;
    const bool ph = (t >= nt0);
    const int qt = ph ? qt1 : qt0;
    const int j = ph ? t - nt0 : t;
    const bool have_next = (t + 1 < 17);
    unsigned short* ps = (wvi < 4) ? (Ks[buf ^ 1] + wvi * 1280)
                                   : (Vs[buf ^ 1] + (wvi - 4) * 1152);
    s16x8 k0n, k1n, v0n, v1n;
    if (have_next) {
      const int jn = (t + 1 >= nt0) ? t + 1 - nt0 : t + 1;
      if (wvi < 4) {
        const unsigned short* kp = qkv + base + (size_t)(jn * 128 + krow) * 768 + 256 + khK * 16;
        k0n = *(const s16x8*)kp;
        k1n = *(const s16x8*)(kp + 8);
      } else {
        const unsigned short* vp = qkv + base + (size_t)(jn * 128 + khv * 64 + lane) * 768 + 512 + dh * 16;
        v0n = *(const s16x8*)vp;
        v1n = *(const s16x8*)(vp + 8);
      }
    }
    // ---- compute: wave handles local cbs 0..cbm (global cb = kh*4+c) ----
    const int rel = qt * 64 + w * 16 - j * 128;
    int cbg = (rel + 15) >> 4; if (cbg > 7) cbg = 7;
    const int cbm = (cbg - kh * 4 > 3) ? 3 : cbg - kh * 4;  // may be < 0
    if (cbm >= 0) {
      const bool fullw = (rel >= kh * 64 + 63);
      f32x4 st[4];
#pragma unroll
      for (int c = 0; c < 4; ++c)
        if (c <= cbm) {
          s16x8 kf = *(const s16x8*)(Ks[buf] + (kh * 64 + c * 16 + l15) * 40 + g * 8);
          f32x4 zz = {};
          st[c] = __builtin_amdgcn_mfma_f32_16x16x32_bf16(kf, ph ? qf1 : qf0, zz, 0, 0, 0);
        }
      float rmax = -3.0e38f;
#pragma unroll
      for (int c = 0; c < 4; ++c)
        if (c <= cbm) {
          if (!fullw) {
#pragma unroll
            for (int r = 0; r < 4; ++r)
              if ((kh * 64 + c * 16 + g * 4 + r) > rel + l15) st[c][r] = -3.0e38f;
          }
#pragma unroll
          for (int r = 0; r < 4; ++r) rmax = fmaxf(rmax, st[c][r]);
        }
      rmax = fmaxf(rmax, __shfl_xor(rmax, 16));
      rmax = fmaxf(rmax, __shfl_xor(rmax, 32));
      const float rs = rmax * scl2;
      float al = 1.0f;
      if (!__all(rs <= mM + 11.5f)) {
        float nm = fmaxf(mM, rs);
        al = fexp2(mM - nm);
        mM = nm;
#pragma unroll
        for (int r = 0; r < 4; ++r) {
          float aw = __shfl(al, g * 4 + r);
          accO[0][r] *= aw;
          accO[1][r] *= aw;
        }
      }
      float rsum = 0.f;
#pragma unroll
      for (int c = 0; c < 4; ++c)
        if (c <= cbm) {
          float e0 = fexp2(fmaf(st[c][0], scl2, -mM));
          float e1 = fexp2(fmaf(st[c][1], scl2, -mM));
          float e2 = fexp2(fmaf(st[c][2], scl2, -mM));
          float e3 = fexp2(fmaf(st[c][3], scl2, -mM));
          rsum += (e0 + e1) + (e2 + e3);
          unsigned long long u = (unsigned long long)cvtpk(e0, e1) |
                                 ((unsigned long long)cvtpk(e2, e3) << 32);
          *(unsigned long long*)(ps + l15 * 72 + c * 16 + g * 4) = u;
        }
      if (cbm < 3 && !(cbm & 1))
        *(unsigned long long*)(ps + l15 * 72 + (cbm + 1) * 16 + g * 4) = 0ULL;
      rsum += __shfl_xor(rsum, 16);
      rsum += __shfl_xor(rsum, 32);
      ls = ls * al + rsum;
      asm volatile("s_waitcnt lgkmcnt(0)" ::: "memory");
      __builtin_amdgcn_sched_barrier(0);
      const int kcm = cbm >> 1;
#pragma unroll
      for (int kc = 0; kc < 2; ++kc)
        if (kc <= kcm) {
          s16x8 pa = *(const s16x8*)(ps + l15 * 72 + kc * 32 + g * 8);
          s16x8 bv0, bv1;
#pragma unroll
          for (int hb = 0; hb < 2; ++hb) {
            const int d = hb * 16 + l15;
            const int kx = (kc * 32 + g * 8) ^ (((d >> 3) & 3) << 4);
            if (hb == 0) bv0 = *(const s16x8*)(Vs[buf] + kh * 2304 + d * 72 + kx);
            else bv1 = *(const s16x8*)(Vs[buf] + kh * 2304 + d * 72 + kx);
          }
          accO[0] = __builtin_amdgcn_mfma_f32_16x16x32_bf16(pa, bv0, accO[0], 0, 0, 0);
          accO[1] = __builtin_amdgcn_mfma_f32_16x16x32_bf16(pa, bv1, accO[1], 0, 0, 0);
        }
    }
    // ---- stage next tile into buf^1 (own region), then barrier ----
    if (have_next) {
      if (wvi < 4) {
        *(s16x8*)(Ks[buf ^ 1] + krow * 40 + khK * 16) = k0n;
        *(s16x8*)(Ks[buf ^ 1] + krow * 40 + khK * 16 + 8) = k1n;
      } else {
        unsigned short* vb = Vs[buf ^ 1] + khv * 2304;
#pragma unroll
        for (int e = 0; e < 8; ++e) {
          int d0 = dh * 16 + e, d1 = dh * 16 + 8 + e;
          vb[d0 * 72 + (lane ^ (((d0 >> 3) & 3) << 4))] = (unsigned short)v0n[e];
          vb[d1 * 72 + (lane ^ (((d1 >> 3) & 3) << 4))] = (unsigned short)v1n[e];
        }
      }
      __syncthreads();
    }
    // ---- phase-0 boundary: flash-combine kh halves, write O(qt0), reset ----
    if (t == nt0 - 1) {
      float* sc = (float*)((wvi < 4) ? (Ks[buf] + wvi * 1280) : (Vs[buf] + (wvi - 4) * 1152));
#pragma unroll
      for (int hb = 0; hb < 2; ++hb)
#pragma unroll
        for (int r = 0; r < 4; ++r) sc[(g * 4 + r) * 32 + hb * 16 + l15] = accO[hb][r];
      if (g == 0) { sc[512 + l15] = mM; sc[528 + l15] = ls; }
      __syncthreads();
      if (kh == 0) {
        const int pw = wvi + 1;
        float* pb = (float*)((pw < 4) ? (Ks[buf] + pw * 1280) : (Vs[buf] + (pw - 4) * 1152));
#pragma unroll
        for (int r = 0; r < 4; ++r) {
          int q = g * 4 + r;
          float mA = __shfl(mM, q), lA = __shfl(ls, q);
          float mB = pb[512 + q], lB = pb[528 + q];
          float M = fmaxf(mA, mB);
          float eA = fexp2(mA - M), eB = fexp2(mB - M);
          float inv = 1.0f / (eA * lA + eB * lB);
          int row = qt0 * 64 + w * 16 + q;
#pragma unroll
          for (int hb = 0; hb < 2; ++hb) {
            float ob = pb[q * 32 + hb * 16 + l15];
            float val = (eA * accO[hb][r] + eB * ob) * inv;
            o[(size_t)(b * TT + row) * DD + hh * 32 + hb * 16 + l15] = f2bf(val);
          }
        }
      }
      __syncthreads();
      accO[0] = f32x4{};
      accO[1] = f32x4{};
      mM = -3.0e38f;
      ls = 0.f;
    }
  }
  // ---- final combine for qt1 (buf of t=16 is 0) ----
  {
    __syncthreads();
    float* sc = (float*)((wvi < 4) ? (Ks[0] + wvi * 1280) : (Vs[0] + (wvi - 4) * 1152));
#pragma unroll
    for (int hb = 0; hb < 2; ++hb)
#pragma unroll
      for (int r = 0; r < 4; ++r) sc[(g * 4 + r) * 32 + hb * 16 + l15] = accO[hb][r];
    if (g == 0) { sc[512 + l15] = mM; sc[528 + l15] = ls; }
    __syncthreads();
    if (kh == 0) {
      const int pw = wvi + 1;
      float* pb = (float*)((pw < 4) ? (Ks[0] + pw * 1280) : (Vs[0] + (pw - 4) * 1152));
#pragma unroll
      for (int r = 0; r < 4; ++r) {
        int q = g * 4 + r;
        float mA = __shfl(mM, q), lA = __shfl(ls, q);
        float mB = pb[512 + q], lB = pb[528 + q];
        float M = fmaxf(mA, mB);
        float eA = fexp2(mA - M), eB = fexp2(mB - M);
        float inv = 1.0f / (eA * lA + eB * lB);
        int row = qt1 * 64 + w * 16 + q;
#pragma unroll
        for (int hb = 0; hb < 2; ++hb) {
          float ob = pb[q * 32 + hb * 16 + l15];
          float val = (eA * accO[hb][r] + eB * ob) * inv;
          o[(size_t)(b * TT + row) * DD + hh * 32 + hb * 16 + l15] = f2bf(val);
        }
      }
    }
  }
}

extern "C" void kernel_launch(void* const* d_in, const int* in_sizes, int n_in,
                              void* d_out, int out_size, void* d_ws, size_t ws_size,
                              hipStream_t stream) {
  const int* x = (const int*)d_in[0];
  const float* tok = (const float*)d_in[1];
  const float* pos = (const float*)d_in[2];
  const float* ln1w = (const float*)d_in[3];
  const float* ln1b = (const float*)d_in[4];
  const float* qkvw = (const float*)d_in[5];
  const float* qkvb = (const float*)d_in[6];
  const float* outw = (const float*)d_in[7];
  const float* outb = (const float*)d_in[8];
  const float* ln2w = (const float*)d_in[9];
  const float* ln2b = (const float*)d_in[10];
  const float* f1w = (const float*)d_in[11];
  const float* f1b = (const float*)d_in[12];
  const float* f2w = (const float*)d_in[13];
  const float* f2b = (const float*)d_in[14];
  const float* lnfw = (const float*)d_in[15];
  const float* lnfb = (const float*)d_in[16];
  const float* hw = (const float*)d_in[17];
  const float* hb = (const float*)d_in[18];

  char* ws = (char*)d_ws;
  float* h = (float*)(ws + 0);                              //  8 MB
  unsigned short* z = (unsigned short*)(ws + 8388608);      //  4 MB
  unsigned short* qkvB = (unsigned short*)(ws + 12582912);  // 12 MB
  unsigned short* ob = (unsigned short*)(ws + 25165824);    //  4 MB
  unsigned short* a1 = (unsigned short*)(ws + 29360128);    // 16 MB
  unsigned short* wAll = (unsigned short*)(ws + 46137344);  // 18 MB (12 layers) or 1.5 MB (fallback)
  const bool bigws = ws_size >= 65142784ULL;
  unsigned short* wh = (unsigned short*)(ws + (bigws ? 65011712 : 47710208));

  if (bigws)
    k_cast_all<<<dim3(768, 12), dim3(256), 0, stream>>>(qkvw, outw, f1w, f2w, wAll);
  k_cast_tr256<<<dim3(256), dim3(256), 0, stream>>>(hw, wh);
  k_embed<<<dim3(2048), dim3(256), 0, stream>>>(x, tok, pos, h);
  k_ln<<<dim3(2048), dim3(256), 0, stream>>>(h, ln1w, ln1b, z);  // layer-0 ln1

  for (int l = 0; l < LL; ++l) {
    unsigned short* wq = wAll + (size_t)(bigws ? l : 0) * 786432;
    unsigned short* wo = wq + 196608;
    unsigned short* w1 = wo + 65536;
    unsigned short* w2 = w1 + 262144;
    if (!bigws)
      k_cast_tr4<<<dim3(1024), dim3(256), 0, stream>>>(
          qkvw + (size_t)l * 196608, outw + (size_t)l * 65536,
          f1w + (size_t)l * 262144, f2w + (size_t)l * 262144, wq, wo, w1, w2);
    k_gemm<0, 2><<<dim3(6, 128), dim3(256), 0, stream>>>(z, wq, qkvb + l * 768, qkvB, nullptr, 8192, 768, 256);
    k_attn<<<dim3(16, 32), dim3(512), 0, stream>>>(qkvB, ob);
    k_gemm_ln<4><<<dim3(256), dim3(256), 0, stream>>>(ob, wo, outb + l * 256, h,
                                                      ln2w + l * 256, ln2b + l * 256, z);
    k_gemm<1, 2><<<dim3(8, 128), dim3(256), 0, stream>>>(z, w1, f1b + l * 1024, a1, nullptr, 8192, 1024, 256);
    const float* nw = (l == LL - 1) ? lnfw : ln1w + (l + 1) * 256;
    const float* nb = (l == LL - 1) ? lnfb : ln1b + (l + 1) * 256;
    k_gemm_ln<16><<<dim3(256), dim3(256), 0, stream>>>(a1, w2, f2b + l * 256, h, nw, nb, z);
  }

  k_gemm<3, 2><<<dim3(2, 128), dim3(256), 0, stream>>>(z, wh, hb, d_out, nullptr, 8192, 256, 256);
}